// Round 1
// baseline (1156.109 us; speedup 1.0000x reference)
//
#include <hip/hip_runtime.h>
#include <hip/hip_bf16.h>

// Problem constants (SymNetDP): B=64, S=4096, NGB=13, NG=48, DIM=3, NCH={8,8,1}
#define BATCH 64
#define SITES 4096
#define NGB 13
#define NGRP 48
#define SDIM 3

// ---------------------------------------------------------------------------
// Workspace layout (floats):
//   GW0 : (8,48,13)     =  4992   @ 0
//   GW1 : (8,48,104)    = 39936   @ 4992
//   GW2 : (48,104)      =  4992   @ 44928
//   Avc : (3,13)        =    39   @ 49920  (padded to 49984)
//   A0  : (B,8,S)       = 2097152 @ 49984
//   A1  : (B,8,S)       = 2097152 @ 2147136
//   A2  : (B,1,S)       =  262144 @ 4244288
// total 4506432 floats = ~17.2 MB
// ---------------------------------------------------------------------------
#define OFF_GW0 0
#define OFF_GW1 4992
#define OFF_GW2 44928
#define OFF_AVC 49920
#define OFF_A0  49984
#define OFF_A1  2147136
#define OFF_A2  4244288

__device__ __forceinline__ float softplus_f(float h) {
    // stable: max(h,0) + log(1+exp(-|h|)); f32-accurate to ~1e-7 rel
    return fmaxf(h, 0.f) + __logf(1.f + __expf(-fabsf(h)));
}

// ---------------------------------------------------------------------------
// Precompute: rotated weights GW0/GW1/GW2 and the collapsed vector-channel
// matrix Avc[d,n] = (1/48) * sum_g (gdiags @ P)[g*3+d, n]
// ---------------------------------------------------------------------------
__global__ __launch_bounds__(256) void precompute_kernel(
    const float* __restrict__ Psi0, const float* __restrict__ Psi1,
    const float* __restrict__ Psi2, const float* __restrict__ wtVC,
    const float* __restrict__ gdiags, const int* __restrict__ perms,
    float* __restrict__ ws)
{
    float* GW0 = ws + OFF_GW0;
    float* GW1 = ws + OFF_GW1;
    float* GW2 = ws + OFF_GW2;
    float* Avc = ws + OFF_AVC;
    int t = blockIdx.x * 256 + threadIdx.x;
    if (t < 4992) {
        // GW0[o][g][j] = Psi0[o, 0, perm[g,j]]
        int j = t % NGB; int og = t / NGB; int g = og % NGRP; int o = og / NGRP;
        GW0[t] = Psi0[o * NGB + perms[g * NGB + j]];
    } else if (t < 44928) {
        int u = t - 4992;
        // GW1[o][g][c*13+j] = Psi1[o, c, perm[g,j]]
        int k = u % 104; int og = u / 104; int g = og % NGRP; int o = og / NGRP;
        int c = k / NGB; int j = k % NGB;
        GW1[u] = Psi1[(o * 8 + c) * NGB + perms[g * NGB + j]];
    } else if (t < 49920) {
        int u = t - 44928;
        // GW2[g][c*13+j] = Psi2[0, c, perm[g,j]]
        int k = u % 104; int g = u / 104; int c = k / NGB; int j = k % NGB;
        GW2[u] = Psi2[c * NGB + perms[g * NGB + j]];
    } else if (t < 49959) {
        int u = t - 49920;          // u = d*13 + n
        int d = u / NGB, n = u % NGB;
        // Wvc = gdiags @ P ; P[g2*3+d2, n] = wtVC[d2, perm[g2, n]]
        // Avc[d,n] = (1/48) sum_g Wvc[g*3+d, n]
        float s = 0.f;
        for (int g = 0; g < NGRP; g++) {
            int row = g * SDIM + d;
            for (int k = 0; k < NGRP * SDIM; k++) {
                int g2 = k / SDIM, d2 = k % SDIM;
                float p = wtVC[d2 * NGB + perms[g2 * NGB + n]];
                s = fmaf(gdiags[row * (NGRP * SDIM) + k], p, s);
            }
        }
        Avc[u] = s * (1.f / 48.f);
    }
}

// ---------------------------------------------------------------------------
// One gconv layer: gather 13 neighbors per input channel, h[o,g] = GW.x + b,
// softplus, mean over g.  Thread = one (b,s) column; weights staged per-o in
// LDS (wave-uniform broadcast reads).
// ---------------------------------------------------------------------------
template<int NCIN, int NCOUT>
__global__ __launch_bounds__(256) void layer_kernel(
    const float* __restrict__ prev,   // (B, NCIN, S)
    const float* __restrict__ GW,     // (NCOUT, 48, NCIN*13)
    const float* __restrict__ bias,   // (NCOUT, 1)
    const int*   __restrict__ NN,     // (13, S)
    float* __restrict__ out)          // (B, NCOUT, S)
{
    constexpr int K = NCIN * NGB;
    __shared__ float w[NGRP * K];

    const int tid = threadIdx.x;
    const int b = blockIdx.x >> 4;                 // S/256 = 16 chunks per b
    const int s = ((blockIdx.x & 15) << 8) + tid;

    int nn[NGB];
#pragma unroll
    for (int j = 0; j < NGB; j++) nn[j] = NN[j * SITES + s];

    float x[K];
#pragma unroll
    for (int c = 0; c < NCIN; c++) {
        const float* p = prev + (size_t)(b * NCIN + c) * SITES;
#pragma unroll
        for (int j = 0; j < NGB; j++) x[c * NGB + j] = p[nn[j]];
    }

    for (int o = 0; o < NCOUT; o++) {
        __syncthreads();
        {
            const float* gsrc = GW + o * NGRP * K;
            for (int i = tid; i < NGRP * K; i += 256) w[i] = gsrc[i];
        }
        __syncthreads();
        const float bo = bias[o];
        float acc = 0.f;
        for (int g = 0; g < NGRP; g++) {
            float h = bo;
            const float* wr = &w[g * K];
#pragma unroll
            for (int k = 0; k < K; k++) h = fmaf(wr[k], x[k], h);
            acc += softplus_f(h);
        }
        out[((size_t)(b * NCOUT) + o) * SITES + s] = acc * (1.f / 48.f);
    }
}

// ---------------------------------------------------------------------------
// Final: out[b,d] = (1/S) * sum_s sw[shell[s]] * sum_n Avc[d,n]*A2[b,NN[n,s]]
// ---------------------------------------------------------------------------
__global__ __launch_bounds__(256) void reduce_kernel(
    const float* __restrict__ A2,     // (B, S)
    const int*   __restrict__ NN,     // (13, S)
    const int*   __restrict__ s2sh,   // (S,)
    const float* __restrict__ sw,     // (NSHELLS,)
    const float* __restrict__ Avc,    // (3, 13)
    float* __restrict__ out)          // (B, 3)
{
    const int b = blockIdx.x;
    const int tid = threadIdx.x;
    const float* a = A2 + (size_t)b * SITES;

    // load Avc into registers (uniform across threads; compiler scalarizes)
    float A0r[NGB], A1r[NGB], A2r[NGB];
#pragma unroll
    for (int n = 0; n < NGB; n++) {
        A0r[n] = Avc[n];
        A1r[n] = Avc[NGB + n];
        A2r[n] = Avc[2 * NGB + n];
    }

    float acc0 = 0.f, acc1 = 0.f, acc2 = 0.f;
    for (int s = tid; s < SITES; s += 256) {
        float y0 = 0.f, y1 = 0.f, y2 = 0.f;
#pragma unroll
        for (int n = 0; n < NGB; n++) {
            float v = a[NN[n * SITES + s]];
            y0 = fmaf(A0r[n], v, y0);
            y1 = fmaf(A1r[n], v, y1);
            y2 = fmaf(A2r[n], v, y2);
        }
        float wgt = sw[s2sh[s]];
        acc0 = fmaf(wgt, y0, acc0);
        acc1 = fmaf(wgt, y1, acc1);
        acc2 = fmaf(wgt, y2, acc2);
    }

    __shared__ float red[3][256];
    red[0][tid] = acc0; red[1][tid] = acc1; red[2][tid] = acc2;
    __syncthreads();
    for (int st = 128; st > 0; st >>= 1) {
        if (tid < st) {
            red[0][tid] += red[0][tid + st];
            red[1][tid] += red[1][tid + st];
            red[2][tid] += red[2][tid + st];
        }
        __syncthreads();
    }
    if (tid == 0) {
        out[b * 3 + 0] = red[0][0] * (1.f / (float)SITES);
        out[b * 3 + 1] = red[1][0] * (1.f / (float)SITES);
        out[b * 3 + 2] = red[2][0] * (1.f / (float)SITES);
    }
}

// ---------------------------------------------------------------------------
extern "C" void kernel_launch(void* const* d_in, const int* in_sizes, int n_in,
                              void* d_out, int out_size, void* d_ws, size_t ws_size,
                              hipStream_t stream)
{
    const float* InStates = (const float*)d_in[0];   // (64,1,4096)
    const float* Psi0     = (const float*)d_in[1];   // (8,1,13)
    const float* bias0    = (const float*)d_in[2];   // (8,1)
    const float* Psi1     = (const float*)d_in[3];   // (8,8,13)
    const float* bias1    = (const float*)d_in[4];   // (8,1)
    const float* Psi2     = (const float*)d_in[5];   // (1,8,13)
    const float* bias2    = (const float*)d_in[6];   // (1,1)
    const float* wtVC     = (const float*)d_in[7];   // (3,13)
    const float* ShellW   = (const float*)d_in[8];   // (8,)
    const float* gdiags   = (const float*)d_in[9];   // (144,144)
    const int*   GnnPerms = (const int*)d_in[10];    // (48,13)
    const int*   NNSites  = (const int*)d_in[11];    // (13,4096)
    const int*   S2Sh     = (const int*)d_in[12];    // (4096,)

    float* ws  = (float*)d_ws;
    float* GW0 = ws + OFF_GW0;
    float* GW1 = ws + OFF_GW1;
    float* GW2 = ws + OFF_GW2;
    float* Avc = ws + OFF_AVC;
    float* A0  = ws + OFF_A0;
    float* A1  = ws + OFF_A1;
    float* A2  = ws + OFF_A2;

    float* out = (float*)d_out;  // (64,3) f32

    // 1) rotated weights + collapsed vector-channel matrix
    precompute_kernel<<<196, 256, 0, stream>>>(Psi0, Psi1, Psi2, wtVC, gdiags,
                                               GnnPerms, ws);

    // 2) three gconv layers (grid = B * S/256 = 1024 blocks)
    layer_kernel<1, 8><<<1024, 256, 0, stream>>>(InStates, GW0, bias0, NNSites, A0);
    layer_kernel<8, 8><<<1024, 256, 0, stream>>>(A0,       GW1, bias1, NNSites, A1);
    layer_kernel<8, 1><<<1024, 256, 0, stream>>>(A1,       GW2, bias2, NNSites, A2);

    // 3) vector channel + shell weighting + site mean
    reduce_kernel<<<BATCH, 256, 0, stream>>>(A2, NNSites, S2Sh, ShellW, Avc, out);
}